// Round 1
// baseline (2369.311 us; speedup 1.0000x reference)
//
#include <hip/hip_runtime.h>
#include <hip/hip_bf16.h>
#include <float.h>

#define NLVL  4
#define KCB   256
#define DIMD  128
#define NROWS 262144

// ---------------------------------------------------------------------------
// Kernel A: per-entry squared norms  c2[l*256+e] = sum_d cb[l][e][d]^2
// 1024 entries total; 4 blocks x 256 threads, thread-per-entry.
// ---------------------------------------------------------------------------
__global__ __launch_bounds__(256) void rq_c2_kernel(const float* __restrict__ cb,
                                                    float* __restrict__ c2) {
    int e = blockIdx.x * 256 + threadIdx.x;   // 0..1023, exact
    const float4* p = (const float4*)(cb + (size_t)e * DIMD);
    float s = 0.f;
#pragma unroll
    for (int k = 0; k < DIMD / 4; ++k) {
        float4 v = p[k];
        s = fmaf(v.x, v.x, s);
        s = fmaf(v.y, v.y, s);
        s = fmaf(v.z, v.z, s);
        s = fmaf(v.w, v.w, s);
    }
    c2[e] = s;
}

// ---------------------------------------------------------------------------
// Main kernel: one thread per row. Residual held in 32 float4 registers.
// Distance loop reads codebook rows at wave-uniform addresses (scalar-load
// friendly); argmin is per-thread (strict < ascending index == numpy
// first-occurrence). recon = x - residual_final; codes written as floats.
// ---------------------------------------------------------------------------
__global__ __launch_bounds__(256) void rq_main_kernel(const float* __restrict__ x,
                                                      const float* __restrict__ cb,
                                                      const float* __restrict__ c2,
                                                      float* __restrict__ out) {
    const int row = blockIdx.x * 256 + threadIdx.x;   // grid exact: 262144 rows

    const float4* xr = (const float4*)(x + (size_t)row * DIMD);
    float4 r[DIMD / 4];
#pragma unroll
    for (int k = 0; k < DIMD / 4; ++k) r[k] = xr[k];

    int best[NLVL];

    for (int l = 0; l < NLVL; ++l) {
        const float* cbl = cb + (size_t)l * KCB * DIMD;
        const float* c2l = c2 + l * KCB;

        float bv = FLT_MAX;
        int   bi = 0;

        for (int e0 = 0; e0 < KCB; e0 += 4) {
            const float4* p0 = (const float4*)(cbl + (size_t)(e0 + 0) * DIMD);
            const float4* p1 = (const float4*)(cbl + (size_t)(e0 + 1) * DIMD);
            const float4* p2 = (const float4*)(cbl + (size_t)(e0 + 2) * DIMD);
            const float4* p3 = (const float4*)(cbl + (size_t)(e0 + 3) * DIMD);

            float d0 = 0.f, d1 = 0.f, d2 = 0.f, d3 = 0.f;
#pragma unroll
            for (int k = 0; k < DIMD / 4; ++k) {
                float4 rv = r[k];
                float4 a = p0[k];
                d0 = fmaf(rv.x, a.x, d0); d0 = fmaf(rv.y, a.y, d0);
                d0 = fmaf(rv.z, a.z, d0); d0 = fmaf(rv.w, a.w, d0);
                float4 b = p1[k];
                d1 = fmaf(rv.x, b.x, d1); d1 = fmaf(rv.y, b.y, d1);
                d1 = fmaf(rv.z, b.z, d1); d1 = fmaf(rv.w, b.w, d1);
                float4 c = p2[k];
                d2 = fmaf(rv.x, c.x, d2); d2 = fmaf(rv.y, c.y, d2);
                d2 = fmaf(rv.z, c.z, d2); d2 = fmaf(rv.w, c.w, d2);
                float4 d = p3[k];
                d3 = fmaf(rv.x, d.x, d3); d3 = fmaf(rv.y, d.y, d3);
                d3 = fmaf(rv.z, d.z, d3); d3 = fmaf(rv.w, d.w, d3);
            }

            float t0 = c2l[e0 + 0] - 2.f * d0;
            float t1 = c2l[e0 + 1] - 2.f * d1;
            float t2 = c2l[e0 + 2] - 2.f * d2;
            float t3 = c2l[e0 + 3] - 2.f * d3;
            if (t0 < bv) { bv = t0; bi = e0 + 0; }
            if (t1 < bv) { bv = t1; bi = e0 + 1; }
            if (t2 < bv) { bv = t2; bi = e0 + 2; }
            if (t3 < bv) { bv = t3; bi = e0 + 3; }
        }

        best[l] = bi;

        // residual -= selected entry (per-lane gather; L2-resident codebook)
        const float4* sel = (const float4*)(cbl + (size_t)bi * DIMD);
#pragma unroll
        for (int k = 0; k < DIMD / 4; ++k) {
            float4 s = sel[k];
            r[k].x -= s.x; r[k].y -= s.y; r[k].z -= s.z; r[k].w -= s.w;
        }
    }

    // recon = x - residual_final
    float4* outr = (float4*)(out + (size_t)row * DIMD);
#pragma unroll
    for (int k = 0; k < DIMD / 4; ++k) {
        float4 xv = xr[k];
        float4 o;
        o.x = xv.x - r[k].x;
        o.y = xv.y - r[k].y;
        o.z = xv.z - r[k].z;
        o.w = xv.w - r[k].w;
        outr[k] = o;
    }

    // codes as floats, one float4 per row
    float4 cd;
    cd.x = (float)best[0];
    cd.y = (float)best[1];
    cd.z = (float)best[2];
    cd.w = (float)best[3];
    ((float4*)(out + (size_t)NROWS * DIMD))[row] = cd;
}

extern "C" void kernel_launch(void* const* d_in, const int* in_sizes, int n_in,
                              void* d_out, int out_size, void* d_ws, size_t ws_size,
                              hipStream_t stream) {
    const float* x  = (const float*)d_in[0];
    const float* cb = (const float*)d_in[1];
    float* out = (float*)d_out;
    float* c2  = (float*)d_ws;   // 4096 floats = 16 KB scratch

    rq_c2_kernel<<<NLVL * KCB / 256, 256, 0, stream>>>(cb, c2);
    rq_main_kernel<<<NROWS / 256, 256, 0, stream>>>(x, cb, c2, out);
}

// Round 2
// 842.787 us; speedup vs baseline: 2.8113x; 2.8113x over previous
//
#include <hip/hip_runtime.h>
#include <hip/hip_bf16.h>
#include <float.h>

#define NLVL  4
#define KCB   256
#define DIMD  128
#define NROWS 262144
#define MTILE 128            // rows per workgroup
#define RES_STRIDE 132       // fp32 LDS row stride (pad 4 -> 2-way-free banks)
#define MARGIN 0.5f
#define WLCAP 2048

typedef _Float16 half8  __attribute__((ext_vector_type(8)));
typedef float    floatx4 __attribute__((ext_vector_type(4)));

// ---------------------------------------------------------------------------
// Prep: per-entry ||c||^2 (exact fp32, same arithmetic as R1) + fp16 codebook.
// 1024 entries, thread-per-entry.
// ---------------------------------------------------------------------------
__global__ __launch_bounds__(256) void rq_prep_kernel(const float* __restrict__ cb,
                                                      float* __restrict__ c2,
                                                      _Float16* __restrict__ cbh) {
    int e = blockIdx.x * 256 + threadIdx.x;   // 0..1023
    const float4* p = (const float4*)(cb + (size_t)e * DIMD);
    _Float16* ho = cbh + (size_t)e * DIMD;
    float s = 0.f;
#pragma unroll
    for (int k = 0; k < DIMD / 4; ++k) {
        float4 v = p[k];
        s = fmaf(v.x, v.x, s);
        s = fmaf(v.y, v.y, s);
        s = fmaf(v.z, v.z, s);
        s = fmaf(v.w, v.w, s);
        ho[4 * k + 0] = (_Float16)v.x;
        ho[4 * k + 1] = (_Float16)v.y;
        ho[4 * k + 2] = (_Float16)v.z;
        ho[4 * k + 3] = (_Float16)v.w;
    }
    c2[e] = s;
}

// ---------------------------------------------------------------------------
// Main fused kernel: 128 rows/block, residual fp32 in LDS. Per level:
//   GEMM (mfma 16x16x32 f16, 3% approx)  ->  per-row argmin + margin filter
//   -> exact fp32 refinement of near-ties (bit-identical to R1 arithmetic)
//   -> residual update. Finally recon = x - residual, codes as floats.
// ---------------------------------------------------------------------------
__global__ __launch_bounds__(256, 2) void rq_main_kernel(const float* __restrict__ x,
                                                         const float* __restrict__ cb,
                                                         const float* __restrict__ c2g,
                                                         const _Float16* __restrict__ cbh,
                                                         float* __restrict__ out) {
    __shared__ float res[MTILE * RES_STRIDE];            // 67.6 KB
    __shared__ unsigned long long refine_key[MTILE];     // 1 KB
    __shared__ int codes_lds[MTILE * 4];                 // 2 KB
    __shared__ unsigned int wl[WLCAP];                   // 8 KB
    __shared__ int wl_cnt;

    const int tid  = threadIdx.x;
    const int wave = tid >> 6;
    const int lane = tid & 63;
    const int q    = lane >> 4;     // quad 0..3
    const int c    = lane & 15;     // column / A-row selector
    const int row0 = blockIdx.x * MTILE;

    // ---- stage x tile -> LDS residual (coalesced float4) ----
    for (int i = tid; i < MTILE * DIMD / 4; i += 256) {
        int r_ = i >> 5, c4 = i & 31;
        float4 v = ((const float4*)x)[(size_t)(row0 + r_) * 32 + c4];
        *(float4*)&res[r_ * RES_STRIDE + c4 * 4] = v;
    }
    __syncthreads();

    for (int l = 0; l < NLVL; ++l) {
        // ---- init per-level state ----
        if (tid == 0) wl_cnt = 0;
        if (tid < MTILE) refine_key[tid] = ~0ULL;
        __syncthreads();

        // per-lane c2 for my 16 candidate entries (e = t*16 + c)
        float c2v[16];
#pragma unroll
        for (int t = 0; t < 16; ++t) c2v[t] = c2g[l * KCB + t * 16 + c];

        const _Float16* cbl = cbh + (size_t)l * KCB * DIMD;

        // ---- GEMM: this wave computes rows [wave*32, wave*32+32) x 256 entries ----
        floatx4 acc[2][16];
#pragma unroll
        for (int sp = 0; sp < 2; ++sp)
#pragma unroll
            for (int t = 0; t < 16; ++t)
                acc[sp][t] = (floatx4){0.f, 0.f, 0.f, 0.f};

#pragma unroll
        for (int s = 0; s < 4; ++s) {        // k-steps of 32
            half8 a0, a1;
            {
                const float* pr = &res[(wave * 32 + c) * RES_STRIDE + s * 32 + q * 8];
                float4 u = *(const float4*)pr;
                float4 v = *(const float4*)(pr + 4);
                a0[0] = (_Float16)u.x; a0[1] = (_Float16)u.y;
                a0[2] = (_Float16)u.z; a0[3] = (_Float16)u.w;
                a0[4] = (_Float16)v.x; a0[5] = (_Float16)v.y;
                a0[6] = (_Float16)v.z; a0[7] = (_Float16)v.w;
            }
            {
                const float* pr = &res[(wave * 32 + 16 + c) * RES_STRIDE + s * 32 + q * 8];
                float4 u = *(const float4*)pr;
                float4 v = *(const float4*)(pr + 4);
                a1[0] = (_Float16)u.x; a1[1] = (_Float16)u.y;
                a1[2] = (_Float16)u.z; a1[3] = (_Float16)u.w;
                a1[4] = (_Float16)v.x; a1[5] = (_Float16)v.y;
                a1[6] = (_Float16)v.z; a1[7] = (_Float16)v.w;
            }
#pragma unroll
            for (int t = 0; t < 16; ++t) {
                half8 b = *(const half8*)(cbl + (size_t)(t * 16 + c) * DIMD + s * 32 + q * 8);
                acc[0][t] = __builtin_amdgcn_mfma_f32_16x16x32_f16(a0, b, acc[0][t], 0, 0, 0);
                acc[1][t] = __builtin_amdgcn_mfma_f32_16x16x32_f16(a1, b, acc[1][t], 0, 0, 0);
            }
        }

        // ---- selection: argmin + margin filter, per strip, per acc-reg (row) ----
#pragma unroll
        for (int sp = 0; sp < 2; ++sp) {
#pragma unroll
            for (int r = 0; r < 4; ++r) {
                float bv = FLT_MAX; int be = 0;
#pragma unroll
                for (int t = 0; t < 16; ++t) {
                    float d = c2v[t] - 2.f * acc[sp][t][r];
                    if (d < bv) { bv = d; be = t * 16 + c; }
                }
                // cross-lane argmin over the 16 columns (first-occurrence tiebreak)
#pragma unroll
                for (int m = 1; m < 16; m <<= 1) {
                    float ov = __shfl_xor(bv, m);
                    int   oe = __shfl_xor(be, m);
                    if (ov < bv || (ov == bv && oe < be)) { bv = ov; be = oe; }
                }
                float thr = bv + MARGIN;
                int cnt = 0;
#pragma unroll
                for (int t = 0; t < 16; ++t)
                    cnt += (c2v[t] - 2.f * acc[sp][t][r]) <= thr;
#pragma unroll
                for (int m = 1; m < 16; m <<= 1) cnt += __shfl_xor(cnt, m);

                int row_l = wave * 32 + sp * 16 + q * 4 + r;
                if (c == 0) codes_lds[row_l * 4 + l] = be;
                if (cnt >= 2) {
#pragma unroll
                    for (int t = 0; t < 16; ++t) {
                        float d = c2v[t] - 2.f * acc[sp][t][r];
                        if (d <= thr) {
                            int slot = atomicAdd(&wl_cnt, 1);
                            if (slot < WLCAP) wl[slot] = ((unsigned)row_l << 8) | (unsigned)(t * 16 + c);
                        }
                    }
                }
            }
        }
        __syncthreads();

        // ---- exact fp32 refinement of near-ties (bit-identical to R1's math) ----
        int n = wl_cnt; if (n > WLCAP) n = WLCAP;
        for (int i = tid; i < n; i += 256) {
            unsigned int it = wl[i];
            int row_l = it >> 8, e = it & 255;
            const float* rr = &res[row_l * RES_STRIDE];
            const float* cc = cb + ((size_t)l * KCB + e) * DIMD;
            float d = 0.f;
#pragma unroll
            for (int k = 0; k < DIMD / 4; ++k) {
                float4 rv = *(const float4*)(rr + 4 * k);
                float4 cv = *(const float4*)(cc + 4 * k);
                d = fmaf(rv.x, cv.x, d);
                d = fmaf(rv.y, cv.y, d);
                d = fmaf(rv.z, cv.z, d);
                d = fmaf(rv.w, cv.w, d);
            }
            float dist = c2g[l * KCB + e] - 2.f * d;
            unsigned int ob = __float_as_uint(dist);
            ob = (ob & 0x80000000u) ? ~ob : (ob | 0x80000000u);
            unsigned long long key = ((unsigned long long)ob << 32) | (unsigned int)e;
            atomicMin(&refine_key[row_l], key);
        }
        __syncthreads();

        // ---- residual update: 2 threads/row, 64 floats each ----
        {
            int row_l = tid >> 1, sub = tid & 1;
            int idx;
            unsigned long long k = refine_key[row_l];
            if (k != ~0ULL) idx = (int)(k & 0xFFFFFFFFULL);
            else            idx = codes_lds[row_l * 4 + l];
            if (sub == 0) codes_lds[row_l * 4 + l] = idx;
            const float4* cbr = (const float4*)(cb + ((size_t)l * KCB + idx) * DIMD + sub * 64);
            float* rr = &res[row_l * RES_STRIDE + sub * 64];
#pragma unroll
            for (int j = 0; j < 16; ++j) {
                float4 v = cbr[j];
                float4 u = *(float4*)(rr + 4 * j);
                u.x -= v.x; u.y -= v.y; u.z -= v.z; u.w -= v.w;
                *(float4*)(rr + 4 * j) = u;
            }
        }
        __syncthreads();
    }

    // ---- output: recon = x - residual (coalesced), codes as float4/row ----
    for (int i = tid; i < MTILE * DIMD / 4; i += 256) {
        int r_ = i >> 5, c4 = i & 31;
        float4 xv = ((const float4*)x)[(size_t)(row0 + r_) * 32 + c4];
        float4 rv = *(const float4*)&res[r_ * RES_STRIDE + c4 * 4];
        float4 o;
        o.x = xv.x - rv.x; o.y = xv.y - rv.y;
        o.z = xv.z - rv.z; o.w = xv.w - rv.w;
        ((float4*)out)[(size_t)(row0 + r_) * 32 + c4] = o;
    }
    if (tid < MTILE) {
        const int* cl = &codes_lds[tid * 4];
        float4 cd;
        cd.x = (float)cl[0]; cd.y = (float)cl[1];
        cd.z = (float)cl[2]; cd.w = (float)cl[3];
        ((float4*)(out + (size_t)NROWS * DIMD))[row0 + tid] = cd;
    }
}

extern "C" void kernel_launch(void* const* d_in, const int* in_sizes, int n_in,
                              void* d_out, int out_size, void* d_ws, size_t ws_size,
                              hipStream_t stream) {
    const float* x  = (const float*)d_in[0];
    const float* cb = (const float*)d_in[1];
    float* out = (float*)d_out;

    float*    c2  = (float*)d_ws;                        // 4096 floats = 16 KB
    _Float16* cbh = (_Float16*)((char*)d_ws + 16384);    // 256 KB fp16 codebook

    rq_prep_kernel<<<NLVL * KCB / 256, 256, 0, stream>>>(cb, c2, cbh);
    rq_main_kernel<<<NROWS / MTILE, 256, 0, stream>>>(x, cb, c2, cbh, out);
}